// Round 12
// baseline (844.729 us; speedup 1.0000x reference)
//
#include <hip/hip_runtime.h>
#include <math.h>

#define Bsz 512
#define Nc  81
#define Rtot (Bsz*Nc)     /* 41472 rows */
#define DEG 20
#define Edim 16
#define HD  96
#define NITER 4

typedef __attribute__((ext_vector_type(8))) __bf16 bf16x8;
typedef __attribute__((ext_vector_type(4))) float f32x4;

__device__ __forceinline__ float sigf(float x){ return 1.0f/(1.0f+__expf(-x)); }
__device__ __forceinline__ float tanh_fast(float x){ return 2.0f/(1.0f+__expf(-2.0f*x)) - 1.0f; }

__device__ __forceinline__ unsigned short f2bf(float f){
    union{float f; unsigned u;} v; v.f=f;
    unsigned r = v.u + 0x7fff + ((v.u>>16)&1);
    return (unsigned short)(r>>16);
}
__device__ __forceinline__ float bf2f(unsigned short s){
    union{unsigned u; float f;} v; v.u=((unsigned)s)<<16; return v.f;
}
__device__ __forceinline__ bf16x8 pack8f(const float* x){
    bf16x8 r;
    #pragma unroll
    for (int j=0;j<8;j++) r[j]=(__bf16)x[j];
    return r;
}
__device__ __forceinline__ bf16x8 ldw(const __bf16* p){ return *(const bf16x8*)p; }

/* ---- swizzled LDS tile [16][96] fp32 (XOR 16B-chunk idx with row&7) ---- */
__device__ __forceinline__ int swz(int row, int col){
    return row*96 + ((((col>>2) ^ (row&7))<<2) | (col&3));
}
__device__ __forceinline__ void ldtr8(const float* tp, int row, int c, float* o){
    const int r96 = row*96, rho = row&7;
    const float4 a = *(const float4*)(tp + r96 + ((((c>>2)  ) ^ rho)<<2));
    const float4 b = *(const float4*)(tp + r96 + ((((c>>2)+1) ^ rho)<<2));
    o[0]=a.x;o[1]=a.y;o[2]=a.z;o[3]=a.w;o[4]=b.x;o[5]=b.y;o[6]=b.z;o[7]=b.w;
}
__device__ __forceinline__ bf16x8 packtr8(const float* tp, int row, int c){
    float t[8]; ldtr8(tp,row,c,t); return pack8f(t);
}

/* bf16 transposed-weight offsets inside ws (elements) — [n][k] layouts */
#define OFF_FW1T 0          /* [192][96] */
#define OFF_FW2T 18432
#define OFF_FW3T 27648
#define OFF_GW1T 36864      /* [96][192] */
#define OFF_GW2T 55296
#define OFF_GW3T 64512
#define OFF_WIHT 73728      /* [384][96] */
#define OFF_WHHT 110592
#define OFF_RW1T 147456
#define OFF_RW2T 156672
#define OFF_RW3T 165888     /* [16][96] */
#define OFF_IW1T 167424     /* [96][32] */
#define OFF_IW2T 170496
#define OFF_IW3T 179712
#define WT_TOTAL 188928

/* ---------------- k_prep: bf16 transposed weights ---------------- */
__global__ __launch_bounds__(256) void k_prep(
    const float* __restrict__ fw1, const float* __restrict__ fw2, const float* __restrict__ fw3,
    const float* __restrict__ gw1, const float* __restrict__ gw2, const float* __restrict__ gw3,
    const float* __restrict__ wih, const float* __restrict__ whh,
    const float* __restrict__ rw1, const float* __restrict__ rw2, const float* __restrict__ rw3,
    const float* __restrict__ iw1, const float* __restrict__ iw2, const float* __restrict__ iw3,
    __bf16* __restrict__ wt)
{
    int i = blockIdx.x*256 + threadIdx.x;
    if (i >= WT_TOTAL) return;
    int j = i;
    if (j < 18432){ int n=j/96, k=j-n*96;
        wt[OFF_FW1T+j] = (__bf16)(n<96 ? fw1[k*96+n] : fw1[(96+k)*96+(n-96)]); return; }
    j -= 18432;
    if (j < 9216){ int n=j/96, k=j-n*96; wt[OFF_FW2T+j]=(__bf16)fw2[k*96+n]; return; }
    j -= 9216;
    if (j < 9216){ int n=j/96, k=j-n*96; wt[OFF_FW3T+j]=(__bf16)fw3[k*96+n]; return; }
    j -= 9216;
    if (j < 18432){ int n=j/192, k=j-n*192; wt[OFF_GW1T+j]=(__bf16)gw1[k*96+n]; return; }
    j -= 18432;
    if (j < 9216){ int n=j/96, k=j-n*96; wt[OFF_GW2T+j]=(__bf16)gw2[k*96+n]; return; }
    j -= 9216;
    if (j < 9216){ int n=j/96, k=j-n*96; wt[OFF_GW3T+j]=(__bf16)gw3[k*96+n]; return; }
    j -= 9216;
    if (j < 36864){ int n=j/96, k=j-n*96; wt[OFF_WIHT+j]=(__bf16)wih[k*384+n]; return; }
    j -= 36864;
    if (j < 36864){ int n=j/96, k=j-n*96; wt[OFF_WHHT+j]=(__bf16)whh[k*384+n]; return; }
    j -= 36864;
    if (j < 9216){ int n=j/96, k=j-n*96; wt[OFF_RW1T+j]=(__bf16)rw1[k*96+n]; return; }
    j -= 9216;
    if (j < 9216){ int n=j/96, k=j-n*96; wt[OFF_RW2T+j]=(__bf16)rw2[k*96+n]; return; }
    j -= 9216;
    if (j < 1536){ int n=j/96, k=j-n*96; wt[OFF_RW3T+j]=(__bf16)rw3[k*16+n]; return; }
    j -= 1536;
    if (j < 3072){ int n=j>>5, k=j&31; wt[OFF_IW1T+j]=(__bf16)iw1[(k&15)*96+n]; return; }
    j -= 3072;
    if (j < 9216){ int n=j/96, k=j-n*96; wt[OFF_IW2T+j]=(__bf16)iw2[k*96+n]; return; }
    j -= 9216;
    { int n=j/96, k=j-n*96; wt[OFF_IW3T+j]=(__bf16)iw3[k*96+n]; }
}

/* ---------------- k_prep2: fw2 padded [96][104] for LDS staging ---------------- */
__global__ __launch_bounds__(256) void k_prep2(
    const float* __restrict__ fw2, __bf16* __restrict__ wp)
{
    int i = blockIdx.x*256 + threadIdx.x;
    if (i >= 96*104) return;
    int n=i/104, k=i-n*104;
    wp[i] = (__bf16)((k<96)? fw2[k*96+n] : 0.f);
}

/* ---------------- k_all: full 4-iteration RRN, one block per puzzle ----------------
   6-wave WG, LDS 78.4 KB -> 2 blocks/CU (12 waves/CU, 3 waves/SIMD, ~170-reg cap).
   C state in 24 per-lane registers (C-layout). All weight-streaming loops
   unroll-bounded (R10/R11: keeps demand under the cap). */
__global__ __launch_bounds__(384,3) void k_all(
    const int* __restrict__ grids, const int* __restrict__ nbr,
    const float* __restrict__ c0, const float* __restrict__ embw,
    const __bf16* __restrict__ wt, const __bf16* __restrict__ wp,
    const float* __restrict__ ib1, const float* __restrict__ ib2, const float* __restrict__ ib3,
    const float* __restrict__ fb1, const float* __restrict__ fb2, const float* __restrict__ fb3,
    const float* __restrict__ gb1, const float* __restrict__ gb2, const float* __restrict__ gb3,
    const float* __restrict__ bih, const float* __restrict__ bhh,
    const float* __restrict__ rb1, const float* __restrict__ rb2, const float* __restrict__ rb3,
    float* __restrict__ out)
{
    __shared__ __bf16 bmL[96*104];      /* Bm, padded rows (19968 B) */
    __shared__ __bf16 w2L[96*104];      /* fw2 padded (19968 B) */
    __shared__ float  scr[6*16*96];     /* per-wave transpose scratch (36864 B) */
    __shared__ unsigned nbrB[405];      /* packed neighbor bytes (1620 B) */

    const int tid = threadIdx.x;
    const int wave = tid/64, lane = tid&63;
    const int row16 = lane&15, kgrp = lane>>4, ko = kgrp*8;
    const int p = blockIdx.x;
    const int cellR = wave*16 + row16;
    const int gcell = (cellR < Nc) ? cellR : Nc-1;
    float* tp = scr + wave*(16*96);

    const __bf16 *iw1t=wt+OFF_IW1T, *iw2t=wt+OFF_IW2T, *iw3t=wt+OFF_IW3T;
    const __bf16 *fw1t=wt+OFF_FW1T, *fw3t=wt+OFF_FW3T;
    const __bf16 *gw1t=wt+OFF_GW1T, *gw2t=wt+OFF_GW2T, *gw3t=wt+OFF_GW3T;
    const __bf16 *wiht=wt+OFF_WIHT, *whht=wt+OFF_WHHT;
    const __bf16 *rw1t=wt+OFF_RW1T, *rw2t=wt+OFF_RW2T, *rw3t=wt+OFF_RW3T;

    /* ---- stage fw2 + nbr bytes ---- */
    {
        const int4* s=(const int4*)wp; int4* d=(int4*)w2L;
        for (int i=tid;i<(96*104/8);i+=384) d[i]=s[i];
    }
    for (int i=tid;i<405;i+=384){
        unsigned b0=(unsigned)nbr[4*i], b1=(unsigned)nbr[4*i+1],
                 b2=(unsigned)nbr[4*i+2], b3=(unsigned)nbr[4*i+3];
        nbrB[i] = b0 | (b1<<8) | (b2<<16) | (b3<<24);
    }

    /* ---- persistent state (registers): 36 + 24 ---- */
    bf16x8 xF[3], hF[3];   /* X and H row fragments (A-layout) */
    bf16x8 aBb[3];         /* biased A row fragment (A + f_b1), bf16 */
    float  cC[6][4];       /* LSTM cell state, C-layout per-lane */

    /* ---- C init -> registers ---- */
    #pragma unroll
    for (int nf=0;nf<6;nf++)
        #pragma unroll
        for (int q=0;q<4;q++){
            int cell = wave*16 + kgrp*4 + q;
            cC[nf][q] = (cell<Nc) ? c0[((size_t)p*Nc+cell)*HD + nf*16+row16] : 0.f;
        }

    /* ================= embed + input MLP (hi/lo K=32 layer 1) ================= */
    {
        const int g = grids[p*Nc + gcell];
        const float* ew = embw + g*Edim + (kgrp&1)*8;
        bf16x8 ef;
        #pragma unroll
        for (int j=0;j<8;j++){
            float e = ew[j];
            ef[j] = (kgrp<2) ? (__bf16)e : (__bf16)(e - bf2f(f2bf(e)));
        }
        #pragma unroll 2
        for (int nf=0;nf<6;nf++){
            f32x4 c={0.f,0.f,0.f,0.f};
            c=__builtin_amdgcn_mfma_f32_16x16x32_bf16(ef, ldw(iw1t+(size_t)(nf*16+row16)*32+ko), c,0,0,0);
            float b=ib1[nf*16+row16];
            #pragma unroll
            for (int q=0;q<4;q++) tp[swz(kgrp*4+q,nf*16+row16)]=fmaxf(c[q]+b,0.f);
        }
        bf16x8 ta[3];
        #pragma unroll
        for (int kf=0;kf<3;kf++) ta[kf]=packtr8(tp,row16,kf*32+ko);
        #pragma unroll 2
        for (int nf=0;nf<6;nf++){
            f32x4 c={0.f,0.f,0.f,0.f};
            #pragma unroll
            for (int kf=0;kf<3;kf++)
                c=__builtin_amdgcn_mfma_f32_16x16x32_bf16(ta[kf], ldw(iw2t+(size_t)(nf*16+row16)*HD+kf*32+ko), c,0,0,0);
            float b=ib2[nf*16+row16];
            #pragma unroll
            for (int q=0;q<4;q++) tp[swz(kgrp*4+q,nf*16+row16)]=fmaxf(c[q]+b,0.f);
        }
        #pragma unroll
        for (int kf=0;kf<3;kf++) ta[kf]=packtr8(tp,row16,kf*32+ko);
        #pragma unroll 2
        for (int nf=0;nf<6;nf++){
            f32x4 c={0.f,0.f,0.f,0.f};
            #pragma unroll
            for (int kf=0;kf<3;kf++)
                c=__builtin_amdgcn_mfma_f32_16x16x32_bf16(ta[kf], ldw(iw3t+(size_t)(nf*16+row16)*HD+kf*32+ko), c,0,0,0);
            float b=ib3[nf*16+row16];
            #pragma unroll
            for (int q=0;q<4;q++) tp[swz(kgrp*4+q,nf*16+row16)]=c[q]+b;
        }
        #pragma unroll
        for (int kf=0;kf<3;kf++){ xF[kf]=packtr8(tp,row16,kf*32+ko); hF[kf]=xF[kf]; }
    }
    /* ---- initial A|Bm = h0 @ fw1 ---- */
    {
        #pragma unroll 2
        for (int nf=0;nf<6;nf++){
            f32x4 c={0.f,0.f,0.f,0.f};
            #pragma unroll
            for (int kf=0;kf<3;kf++)
                c=__builtin_amdgcn_mfma_f32_16x16x32_bf16(hF[kf], ldw(fw1t+(size_t)(nf*16+row16)*HD+kf*32+ko), c,0,0,0);
            #pragma unroll
            for (int q=0;q<4;q++) tp[swz(kgrp*4+q,nf*16+row16)]=c[q];
        }
        #pragma unroll
        for (int kf=0;kf<3;kf++){
            float h[8]; ldtr8(tp,row16,kf*32+ko,h);
            #pragma unroll
            for (int j=0;j<8;j++) h[j]+=fb1[kf*32+ko+j];
            aBb[kf]=pack8f(h);
        }
        #pragma unroll 2
        for (int nf=6;nf<12;nf++){
            f32x4 c={0.f,0.f,0.f,0.f};
            #pragma unroll
            for (int kf=0;kf<3;kf++)
                c=__builtin_amdgcn_mfma_f32_16x16x32_bf16(hF[kf], ldw(fw1t+(size_t)(nf*16+row16)*HD+kf*32+ko), c,0,0,0);
            int col=(nf-6)*16+row16;
            #pragma unroll
            for (int q=0;q<4;q++) bmL[(wave*16+kgrp*4+q)*104 + col]=(__bf16)c[q];
        }
    }
    __syncthreads();   /* Bm + w2L + nbrB visible */

    /* ================= iteration loop ================= */
    #pragma unroll 1
    for (int it=0; it<NITER; ++it){
        /* ---------- EDGE ---------- */
        bf16x8 mF[3];
        {
            float b2c[6], b3c[6];
            #pragma unroll
            for (int nf=0;nf<6;nf++){ b2c[nf]=fb2[nf*16+row16]; b3c[nf]=20.0f*fb3[nf*16+row16]; }
            f32x4 acc[6];
            #pragma unroll
            for (int nf=0;nf<6;nf++) acc[nf]=(f32x4){0.f,0.f,0.f,0.f};
            const unsigned char* nbp = (const unsigned char*)nbrB;
            #pragma unroll 2
            for (int d=0; d<DEG; d++){
                int j = nbp[gcell*DEG + d];
                const __bf16* vb = bmL + j*104 + ko;
                bf16x8 xf[3];
                #pragma unroll
                for (int kf=0;kf<3;kf++){
                    bf16x8 v = ldw(vb + kf*32);
                    float t[8];
                    #pragma unroll
                    for (int jj=0;jj<8;jj++) t[jj]=fmaxf((float)aBb[kf][jj] + (float)v[jj], 0.f);
                    xf[kf]=pack8f(t);
                }
                #pragma unroll
                for (int g2=0; g2<2; g2++){
                    f32x4 c[3];
                    #pragma unroll
                    for (int nf=0;nf<3;nf++) c[nf]=(f32x4){0.f,0.f,0.f,0.f};
                    #pragma unroll
                    for (int kf=0;kf<3;kf++)
                        #pragma unroll
                        for (int nf=0;nf<3;nf++)
                            c[nf]=__builtin_amdgcn_mfma_f32_16x16x32_bf16(xf[kf],
                                ldw(w2L+(size_t)((g2*3+nf)*16+row16)*104+kf*32+ko), c[nf],0,0,0);
                    #pragma unroll
                    for (int nf=0;nf<3;nf++)
                        #pragma unroll
                        for (int q=0;q<4;q++)
                            acc[g2*3+nf][q]+=fmaxf(c[nf][q]+b2c[g2*3+nf],0.f);
                }
            }
            /* layer 3 with hi/lo split */
            #pragma unroll
            for (int nf=0;nf<6;nf++)
                #pragma unroll
                for (int q=0;q<4;q++) tp[swz(kgrp*4+q,nf*16+row16)]=acc[nf][q];
            f32x4 c2[6];
            #pragma unroll
            for (int nf=0;nf<6;nf++) c2[nf]=(f32x4){0.f,0.f,0.f,0.f};
            #pragma unroll
            for (int kf=0;kf<3;kf++){
                float h[8]; ldtr8(tp,row16,kf*32+ko,h);
                bf16x8 hif, lof;
                #pragma unroll
                for (int j=0;j<8;j++){
                    unsigned short hs=f2bf(h[j]);
                    union{unsigned short s; __bf16 b;} u; u.s=hs;
                    hif[j]=u.b; lof[j]=(__bf16)(h[j]-bf2f(hs));
                }
                #pragma unroll 2
                for (int nf=0;nf<6;nf++){
                    bf16x8 w3f = ldw(fw3t + (size_t)(nf*16+row16)*HD + kf*32+ko);
                    c2[nf]=__builtin_amdgcn_mfma_f32_16x16x32_bf16(hif,w3f,c2[nf],0,0,0);
                    c2[nf]=__builtin_amdgcn_mfma_f32_16x16x32_bf16(lof,w3f,c2[nf],0,0,0);
                }
            }
            #pragma unroll
            for (int nf=0;nf<6;nf++)
                #pragma unroll
                for (int q=0;q<4;q++) tp[swz(kgrp*4+q,nf*16+row16)]=c2[nf][q]+b3c[nf];
            #pragma unroll
            for (int kf=0;kf<3;kf++) mF[kf]=packtr8(tp,row16,kf*32+ko);
        }
        __syncthreads();   /* all waves done reading bmL */

        /* ---------- g-MLP ---------- */
        bf16x8 xinF[3];
        {
            #pragma unroll 2
            for (int nf=0;nf<6;nf++){
                f32x4 c={0.f,0.f,0.f,0.f};
                #pragma unroll
                for (int kf=0;kf<3;kf++){
                    c=__builtin_amdgcn_mfma_f32_16x16x32_bf16(xF[kf], ldw(gw1t+(size_t)(nf*16+row16)*192+kf*32+ko), c,0,0,0);
                    c=__builtin_amdgcn_mfma_f32_16x16x32_bf16(mF[kf], ldw(gw1t+(size_t)(nf*16+row16)*192+96+kf*32+ko), c,0,0,0);
                }
                float b=gb1[nf*16+row16];
                #pragma unroll
                for (int q=0;q<4;q++) tp[swz(kgrp*4+q,nf*16+row16)]=fmaxf(c[q]+b,0.f);
            }
            bf16x8 ta[3];
            #pragma unroll
            for (int kf=0;kf<3;kf++) ta[kf]=packtr8(tp,row16,kf*32+ko);
            #pragma unroll 2
            for (int nf=0;nf<6;nf++){
                f32x4 c={0.f,0.f,0.f,0.f};
                #pragma unroll
                for (int kf=0;kf<3;kf++)
                    c=__builtin_amdgcn_mfma_f32_16x16x32_bf16(ta[kf], ldw(gw2t+(size_t)(nf*16+row16)*HD+kf*32+ko), c,0,0,0);
                float b=gb2[nf*16+row16];
                #pragma unroll
                for (int q=0;q<4;q++) tp[swz(kgrp*4+q,nf*16+row16)]=fmaxf(c[q]+b,0.f);
            }
            #pragma unroll
            for (int kf=0;kf<3;kf++) ta[kf]=packtr8(tp,row16,kf*32+ko);
            #pragma unroll 2
            for (int nf=0;nf<6;nf++){
                f32x4 c={0.f,0.f,0.f,0.f};
                #pragma unroll
                for (int kf=0;kf<3;kf++)
                    c=__builtin_amdgcn_mfma_f32_16x16x32_bf16(ta[kf], ldw(gw3t+(size_t)(nf*16+row16)*HD+kf*32+ko), c,0,0,0);
                float b=gb3[nf*16+row16];
                #pragma unroll
                for (int q=0;q<4;q++) tp[swz(kgrp*4+q,nf*16+row16)]=c[q]+b;
            }
            #pragma unroll
            for (int kf=0;kf<3;kf++) xinF[kf]=packtr8(tp,row16,kf*32+ko);
        }

        /* ---------- LSTM gates: per-nf, all 4 gates inside (R11 form, C in regs) ---------- */
        {
            #pragma unroll 1
            for (int nf=0;nf<6;nf++){
                const int col = nf*16+row16;
                f32x4 ci={0.f,0.f,0.f,0.f}, cf2={0.f,0.f,0.f,0.f},
                      cg={0.f,0.f,0.f,0.f}, co={0.f,0.f,0.f,0.f};
                #pragma unroll
                for (int kf=0;kf<3;kf++){
                    const int kk = kf*32+ko;
                    ci =__builtin_amdgcn_mfma_f32_16x16x32_bf16(xinF[kf], ldw(wiht+(size_t)(  0+col)*HD+kk), ci ,0,0,0);
                    ci =__builtin_amdgcn_mfma_f32_16x16x32_bf16(hF[kf],   ldw(whht+(size_t)(  0+col)*HD+kk), ci ,0,0,0);
                    cf2=__builtin_amdgcn_mfma_f32_16x16x32_bf16(xinF[kf], ldw(wiht+(size_t)( 96+col)*HD+kk), cf2,0,0,0);
                    cf2=__builtin_amdgcn_mfma_f32_16x16x32_bf16(hF[kf],   ldw(whht+(size_t)( 96+col)*HD+kk), cf2,0,0,0);
                    cg =__builtin_amdgcn_mfma_f32_16x16x32_bf16(xinF[kf], ldw(wiht+(size_t)(192+col)*HD+kk), cg ,0,0,0);
                    cg =__builtin_amdgcn_mfma_f32_16x16x32_bf16(hF[kf],   ldw(whht+(size_t)(192+col)*HD+kk), cg ,0,0,0);
                    co =__builtin_amdgcn_mfma_f32_16x16x32_bf16(xinF[kf], ldw(wiht+(size_t)(288+col)*HD+kk), co ,0,0,0);
                    co =__builtin_amdgcn_mfma_f32_16x16x32_bf16(hF[kf],   ldw(whht+(size_t)(288+col)*HD+kk), co ,0,0,0);
                }
                float bi=bih[    col]+bhh[    col];
                float bf=bih[ 96+col]+bhh[ 96+col];
                float bg=bih[192+col]+bhh[192+col];
                float bo=bih[288+col]+bhh[288+col];
                #pragma unroll
                for (int q=0;q<4;q++){
                    float cnew = sigf(cf2[q]+bf)*cC[nf][q] + sigf(ci[q]+bi)*tanh_fast(cg[q]+bg);
                    cC[nf][q]=cnew;
                    float h2v = sigf(co[q]+bo)*tanh_fast(cnew);
                    tp[swz(kgrp*4+q, col)]=h2v;
                }
            }
            #pragma unroll
            for (int kf=0;kf<3;kf++) hF[kf]=packtr8(tp,row16,kf*32+ko);
        }

        /* ---------- next-iter A|Bm ---------- */
        if (it < NITER-1){
            #pragma unroll 2
            for (int nf=0;nf<6;nf++){
                f32x4 c={0.f,0.f,0.f,0.f};
                #pragma unroll
                for (int kf=0;kf<3;kf++)
                    c=__builtin_amdgcn_mfma_f32_16x16x32_bf16(hF[kf], ldw(fw1t+(size_t)(nf*16+row16)*HD+kf*32+ko), c,0,0,0);
                #pragma unroll
                for (int q=0;q<4;q++) tp[swz(kgrp*4+q,nf*16+row16)]=c[q];
            }
            #pragma unroll
            for (int kf=0;kf<3;kf++){
                float h[8]; ldtr8(tp,row16,kf*32+ko,h);
                #pragma unroll
                for (int j=0;j<8;j++) h[j]+=fb1[kf*32+ko+j];
                aBb[kf]=pack8f(h);
            }
            #pragma unroll 2
            for (int nf=6;nf<12;nf++){
                f32x4 c={0.f,0.f,0.f,0.f};
                #pragma unroll
                for (int kf=0;kf<3;kf++)
                    c=__builtin_amdgcn_mfma_f32_16x16x32_bf16(hF[kf], ldw(fw1t+(size_t)(nf*16+row16)*HD+kf*32+ko), c,0,0,0);
                int col=(nf-6)*16+row16;
                #pragma unroll
                for (int q=0;q<4;q++) bmL[(wave*16+kgrp*4+q)*104 + col]=(__bf16)c[q];
            }
        }

        /* ---------- readout MLP -> out ---------- */
        {
            #pragma unroll 2
            for (int nf=0;nf<6;nf++){
                f32x4 c={0.f,0.f,0.f,0.f};
                #pragma unroll
                for (int kf=0;kf<3;kf++)
                    c=__builtin_amdgcn_mfma_f32_16x16x32_bf16(hF[kf], ldw(rw1t+(size_t)(nf*16+row16)*HD+kf*32+ko), c,0,0,0);
                float b=rb1[nf*16+row16];
                #pragma unroll
                for (int q=0;q<4;q++) tp[swz(kgrp*4+q,nf*16+row16)]=fmaxf(c[q]+b,0.f);
            }
            bf16x8 ta[3];
            #pragma unroll
            for (int kf=0;kf<3;kf++) ta[kf]=packtr8(tp,row16,kf*32+ko);
            #pragma unroll 2
            for (int nf=0;nf<6;nf++){
                f32x4 c={0.f,0.f,0.f,0.f};
                #pragma unroll
                for (int kf=0;kf<3;kf++)
                    c=__builtin_amdgcn_mfma_f32_16x16x32_bf16(ta[kf], ldw(rw2t+(size_t)(nf*16+row16)*HD+kf*32+ko), c,0,0,0);
                float b=rb2[nf*16+row16];
                #pragma unroll
                for (int q=0;q<4;q++) tp[swz(kgrp*4+q,nf*16+row16)]=fmaxf(c[q]+b,0.f);
            }
            #pragma unroll
            for (int kf=0;kf<3;kf++) ta[kf]=packtr8(tp,row16,kf*32+ko);
            f32x4 c={0.f,0.f,0.f,0.f};
            #pragma unroll
            for (int kf=0;kf<3;kf++)
                c=__builtin_amdgcn_mfma_f32_16x16x32_bf16(ta[kf], ldw(rw3t+(size_t)row16*HD+kf*32+ko), c,0,0,0);
            float b=rb3[row16];
            #pragma unroll
            for (int q=0;q<4;q++){
                int cell = wave*16 + kgrp*4 + q;
                if (cell < Nc)
                    out[((size_t)it*Rtot + (size_t)p*Nc + cell)*Edim + row16] = c[q]+b;
            }
        }
        __syncthreads();   /* new Bm written before next iter's edge reads */
    }
}

extern "C" void kernel_launch(void* const* d_in, const int* in_sizes, int n_in,
                              void* d_out, int out_size, void* d_ws, size_t ws_size,
                              hipStream_t stream) {
    const int*   grids  = (const int*)  d_in[0];
    const int*   nbr    = (const int*)  d_in[1];
    const float* c0     = (const float*)d_in[3];
    const float* embw   = (const float*)d_in[4];
    const float* in_w1  = (const float*)d_in[5];
    const float* in_b1  = (const float*)d_in[6];
    const float* in_w2  = (const float*)d_in[7];
    const float* in_b2  = (const float*)d_in[8];
    const float* in_w3  = (const float*)d_in[9];
    const float* in_b3  = (const float*)d_in[10];
    const float* f_w1   = (const float*)d_in[11];
    const float* f_b1   = (const float*)d_in[12];
    const float* f_w2   = (const float*)d_in[13];
    const float* f_b2   = (const float*)d_in[14];
    const float* f_w3   = (const float*)d_in[15];
    const float* f_b3   = (const float*)d_in[16];
    const float* g_w1   = (const float*)d_in[17];
    const float* g_b1   = (const float*)d_in[18];
    const float* g_w2   = (const float*)d_in[19];
    const float* g_b2   = (const float*)d_in[20];
    const float* g_w3   = (const float*)d_in[21];
    const float* g_b3   = (const float*)d_in[22];
    const float* wih    = (const float*)d_in[23];
    const float* whh    = (const float*)d_in[24];
    const float* bih    = (const float*)d_in[25];
    const float* bhh    = (const float*)d_in[26];
    const float* r_w1   = (const float*)d_in[27];
    const float* r_b1   = (const float*)d_in[28];
    const float* r_w2   = (const float*)d_in[29];
    const float* r_b2   = (const float*)d_in[30];
    const float* r_w3   = (const float*)d_in[31];
    const float* r_b3   = (const float*)d_in[32];

    __bf16* wt = (__bf16*)d_ws;
    __bf16* wp = wt + WT_TOTAL;
    float* out = (float*)d_out;

    hipLaunchKernelGGL(k_prep, dim3((WT_TOTAL+255)/256), dim3(256), 0, stream,
        f_w1, f_w2, f_w3, g_w1, g_w2, g_w3, wih, whh, r_w1, r_w2, r_w3,
        in_w1, in_w2, in_w3, wt);
    hipLaunchKernelGGL(k_prep2, dim3((96*104+255)/256), dim3(256), 0, stream,
        f_w2, wp);

    hipLaunchKernelGGL(k_all, dim3(Bsz), dim3(384), 0, stream,
        grids, nbr, c0, embw, wt, wp,
        in_b1, in_b2, in_b3,
        f_b1, f_b2, f_b3,
        g_b1, g_b2, g_b3,
        bih, bhh,
        r_b1, r_b2, r_b3,
        out);
}

// Round 13
// 442.832 us; speedup vs baseline: 1.9076x; 1.9076x over previous
//
#include <hip/hip_runtime.h>
#include <math.h>

#define Bsz 512
#define Nc  81
#define Rtot (Bsz*Nc)     /* 41472 rows */
#define DEG 20
#define Edim 16
#define HD  96
#define NITER 4

typedef __attribute__((ext_vector_type(8))) __bf16 bf16x8;
typedef __attribute__((ext_vector_type(4))) float f32x4;

__device__ __forceinline__ float sigf(float x){ return 1.0f/(1.0f+__expf(-x)); }
__device__ __forceinline__ float tanh_fast(float x){ return 2.0f/(1.0f+__expf(-2.0f*x)) - 1.0f; }

__device__ __forceinline__ unsigned short f2bf(float f){
    union{float f; unsigned u;} v; v.f=f;
    unsigned r = v.u + 0x7fff + ((v.u>>16)&1);
    return (unsigned short)(r>>16);
}
__device__ __forceinline__ float bf2f(unsigned short s){
    union{unsigned u; float f;} v; v.u=((unsigned)s)<<16; return v.f;
}
__device__ __forceinline__ bf16x8 pack8f(const float* x){
    bf16x8 r;
    #pragma unroll
    for (int j=0;j<8;j++) r[j]=(__bf16)x[j];
    return r;
}
__device__ __forceinline__ bf16x8 ldw(const __bf16* p){ return *(const bf16x8*)p; }

/* ---- swizzled LDS tile [16][96] fp32 (XOR 16B-chunk idx with row&7) ---- */
__device__ __forceinline__ int swz(int row, int col){
    return row*96 + ((((col>>2) ^ (row&7))<<2) | (col&3));
}
__device__ __forceinline__ void ldtr8(const float* tp, int row, int c, float* o){
    const int r96 = row*96, rho = row&7;
    const float4 a = *(const float4*)(tp + r96 + ((((c>>2)  ) ^ rho)<<2));
    const float4 b = *(const float4*)(tp + r96 + ((((c>>2)+1) ^ rho)<<2));
    o[0]=a.x;o[1]=a.y;o[2]=a.z;o[3]=a.w;o[4]=b.x;o[5]=b.y;o[6]=b.z;o[7]=b.w;
}
__device__ __forceinline__ bf16x8 packtr8(const float* tp, int row, int c){
    float t[8]; ldtr8(tp,row,c,t); return pack8f(t);
}

/* bf16 transposed-weight offsets inside ws (elements) — [n][k] layouts */
#define OFF_FW1T 0          /* [192][96] */
#define OFF_FW2T 18432
#define OFF_FW3T 27648
#define OFF_GW1T 36864      /* [96][192] */
#define OFF_GW2T 55296
#define OFF_GW3T 64512
#define OFF_WIHT 73728      /* [384][96] */
#define OFF_WHHT 110592
#define OFF_RW1T 147456
#define OFF_RW2T 156672
#define OFF_RW3T 165888     /* [16][96] */
#define OFF_IW1T 167424     /* [96][32] */
#define OFF_IW2T 170496
#define OFF_IW3T 179712
#define WT_TOTAL 188928

/* ---------------- k_prep: bf16 transposed weights ---------------- */
__global__ __launch_bounds__(256) void k_prep(
    const float* __restrict__ fw1, const float* __restrict__ fw2, const float* __restrict__ fw3,
    const float* __restrict__ gw1, const float* __restrict__ gw2, const float* __restrict__ gw3,
    const float* __restrict__ wih, const float* __restrict__ whh,
    const float* __restrict__ rw1, const float* __restrict__ rw2, const float* __restrict__ rw3,
    const float* __restrict__ iw1, const float* __restrict__ iw2, const float* __restrict__ iw3,
    __bf16* __restrict__ wt)
{
    int i = blockIdx.x*256 + threadIdx.x;
    if (i >= WT_TOTAL) return;
    int j = i;
    if (j < 18432){ int n=j/96, k=j-n*96;
        wt[OFF_FW1T+j] = (__bf16)(n<96 ? fw1[k*96+n] : fw1[(96+k)*96+(n-96)]); return; }
    j -= 18432;
    if (j < 9216){ int n=j/96, k=j-n*96; wt[OFF_FW2T+j]=(__bf16)fw2[k*96+n]; return; }
    j -= 9216;
    if (j < 9216){ int n=j/96, k=j-n*96; wt[OFF_FW3T+j]=(__bf16)fw3[k*96+n]; return; }
    j -= 9216;
    if (j < 18432){ int n=j/192, k=j-n*192; wt[OFF_GW1T+j]=(__bf16)gw1[k*96+n]; return; }
    j -= 18432;
    if (j < 9216){ int n=j/96, k=j-n*96; wt[OFF_GW2T+j]=(__bf16)gw2[k*96+n]; return; }
    j -= 9216;
    if (j < 9216){ int n=j/96, k=j-n*96; wt[OFF_GW3T+j]=(__bf16)gw3[k*96+n]; return; }
    j -= 9216;
    if (j < 36864){ int n=j/96, k=j-n*96; wt[OFF_WIHT+j]=(__bf16)wih[k*384+n]; return; }
    j -= 36864;
    if (j < 36864){ int n=j/96, k=j-n*96; wt[OFF_WHHT+j]=(__bf16)whh[k*384+n]; return; }
    j -= 36864;
    if (j < 9216){ int n=j/96, k=j-n*96; wt[OFF_RW1T+j]=(__bf16)rw1[k*96+n]; return; }
    j -= 9216;
    if (j < 9216){ int n=j/96, k=j-n*96; wt[OFF_RW2T+j]=(__bf16)rw2[k*96+n]; return; }
    j -= 9216;
    if (j < 1536){ int n=j/96, k=j-n*96; wt[OFF_RW3T+j]=(__bf16)rw3[k*16+n]; return; }
    j -= 1536;
    if (j < 3072){ int n=j>>5, k=j&31; wt[OFF_IW1T+j]=(__bf16)iw1[(k&15)*96+n]; return; }
    j -= 3072;
    if (j < 9216){ int n=j/96, k=j-n*96; wt[OFF_IW2T+j]=(__bf16)iw2[k*96+n]; return; }
    j -= 9216;
    { int n=j/96, k=j-n*96; wt[OFF_IW3T+j]=(__bf16)iw3[k*96+n]; }
}

/* ---------------- k_prep2: fw2 padded [96][104] for LDS staging ---------------- */
__global__ __launch_bounds__(256) void k_prep2(
    const float* __restrict__ fw2, __bf16* __restrict__ wp)
{
    int i = blockIdx.x*256 + threadIdx.x;
    if (i >= 96*104) return;
    int n=i/104, k=i-n*104;
    wp[i] = (__bf16)((k<96)? fw2[k*96+n] : 0.f);
}

/* ---------------- k_all: full 4-iteration RRN, one block per puzzle ----------------
   R11 champion structure (no spills, 449 us) + edge-gather prefetch (R5 pattern).
   6-wave WG + 117KB LDS -> 1 block/CU, 2 waves/SIMD cap -> 256 unified regs.
   All weight-streaming nf-loops unroll-bounded; LSTM per-nf 4-gate form. */
__global__ __launch_bounds__(384,2) void k_all(
    const int* __restrict__ grids, const int* __restrict__ nbr,
    const float* __restrict__ c0, const float* __restrict__ embw,
    const __bf16* __restrict__ wt, const __bf16* __restrict__ wp,
    const float* __restrict__ ib1, const float* __restrict__ ib2, const float* __restrict__ ib3,
    const float* __restrict__ fb1, const float* __restrict__ fb2, const float* __restrict__ fb3,
    const float* __restrict__ gb1, const float* __restrict__ gb2, const float* __restrict__ gb3,
    const float* __restrict__ bih, const float* __restrict__ bhh,
    const float* __restrict__ rb1, const float* __restrict__ rb2, const float* __restrict__ rb3,
    float* __restrict__ out)
{
    __shared__ __bf16 bmL[96*104];      /* Bm, padded rows (19968 B) */
    __shared__ __bf16 w2L[96*104];      /* fw2 padded (19968 B) */
    __shared__ float  scr[6*16*96];     /* per-wave transpose scratch (36864 B) */
    __shared__ float  cL[96*100];       /* LSTM cell state (38400 B) */
    __shared__ unsigned nbrB[405];      /* packed neighbor bytes (1620 B) */

    const int tid = threadIdx.x;
    const int wave = tid/64, lane = tid&63;
    const int row16 = lane&15, kgrp = lane>>4, ko = kgrp*8;
    const int p = blockIdx.x;
    const int cellR = wave*16 + row16;
    const int gcell = (cellR < Nc) ? cellR : Nc-1;
    float* tp = scr + wave*(16*96);

    const __bf16 *iw1t=wt+OFF_IW1T, *iw2t=wt+OFF_IW2T, *iw3t=wt+OFF_IW3T;
    const __bf16 *fw1t=wt+OFF_FW1T, *fw3t=wt+OFF_FW3T;
    const __bf16 *gw1t=wt+OFF_GW1T, *gw2t=wt+OFF_GW2T, *gw3t=wt+OFF_GW3T;
    const __bf16 *wiht=wt+OFF_WIHT, *whht=wt+OFF_WHHT;
    const __bf16 *rw1t=wt+OFF_RW1T, *rw2t=wt+OFF_RW2T, *rw3t=wt+OFF_RW3T;

    /* ---- stage fw2 + nbr bytes ---- */
    {
        const int4* s=(const int4*)wp; int4* d=(int4*)w2L;
        for (int i=tid;i<(96*104/8);i+=384) d[i]=s[i];
    }
    for (int i=tid;i<405;i+=384){
        unsigned b0=(unsigned)nbr[4*i], b1=(unsigned)nbr[4*i+1],
                 b2=(unsigned)nbr[4*i+2], b3=(unsigned)nbr[4*i+3];
        nbrB[i] = b0 | (b1<<8) | (b2<<16) | (b3<<24);
    }

    /* ---- persistent state (registers) ---- */
    bf16x8 xF[3], hF[3];   /* X and H row fragments (A-layout) */
    bf16x8 aBb[3];         /* biased A row fragment (A + f_b1), bf16 */

    /* ---- C init -> LDS (same-lane r/w) ---- */
    #pragma unroll
    for (int nf=0;nf<6;nf++)
        #pragma unroll
        for (int q=0;q<4;q++){
            int cell = wave*16 + kgrp*4 + q;
            cL[cell*100 + nf*16+row16] = (cell<Nc) ? c0[((size_t)p*Nc+cell)*HD + nf*16+row16] : 0.f;
        }

    /* ================= embed + input MLP (hi/lo K=32 layer 1) ================= */
    {
        const int g = grids[p*Nc + gcell];
        const float* ew = embw + g*Edim + (kgrp&1)*8;
        bf16x8 ef;
        #pragma unroll
        for (int j=0;j<8;j++){
            float e = ew[j];
            ef[j] = (kgrp<2) ? (__bf16)e : (__bf16)(e - bf2f(f2bf(e)));
        }
        #pragma unroll 2
        for (int nf=0;nf<6;nf++){
            f32x4 c={0.f,0.f,0.f,0.f};
            c=__builtin_amdgcn_mfma_f32_16x16x32_bf16(ef, ldw(iw1t+(size_t)(nf*16+row16)*32+ko), c,0,0,0);
            float b=ib1[nf*16+row16];
            #pragma unroll
            for (int q=0;q<4;q++) tp[swz(kgrp*4+q,nf*16+row16)]=fmaxf(c[q]+b,0.f);
        }
        bf16x8 ta[3];
        #pragma unroll
        for (int kf=0;kf<3;kf++) ta[kf]=packtr8(tp,row16,kf*32+ko);
        #pragma unroll 2
        for (int nf=0;nf<6;nf++){
            f32x4 c={0.f,0.f,0.f,0.f};
            #pragma unroll
            for (int kf=0;kf<3;kf++)
                c=__builtin_amdgcn_mfma_f32_16x16x32_bf16(ta[kf], ldw(iw2t+(size_t)(nf*16+row16)*HD+kf*32+ko), c,0,0,0);
            float b=ib2[nf*16+row16];
            #pragma unroll
            for (int q=0;q<4;q++) tp[swz(kgrp*4+q,nf*16+row16)]=fmaxf(c[q]+b,0.f);
        }
        #pragma unroll
        for (int kf=0;kf<3;kf++) ta[kf]=packtr8(tp,row16,kf*32+ko);
        #pragma unroll 2
        for (int nf=0;nf<6;nf++){
            f32x4 c={0.f,0.f,0.f,0.f};
            #pragma unroll
            for (int kf=0;kf<3;kf++)
                c=__builtin_amdgcn_mfma_f32_16x16x32_bf16(ta[kf], ldw(iw3t+(size_t)(nf*16+row16)*HD+kf*32+ko), c,0,0,0);
            float b=ib3[nf*16+row16];
            #pragma unroll
            for (int q=0;q<4;q++) tp[swz(kgrp*4+q,nf*16+row16)]=c[q]+b;
        }
        #pragma unroll
        for (int kf=0;kf<3;kf++){ xF[kf]=packtr8(tp,row16,kf*32+ko); hF[kf]=xF[kf]; }
    }
    /* ---- initial A|Bm = h0 @ fw1 ---- */
    {
        #pragma unroll 2
        for (int nf=0;nf<6;nf++){
            f32x4 c={0.f,0.f,0.f,0.f};
            #pragma unroll
            for (int kf=0;kf<3;kf++)
                c=__builtin_amdgcn_mfma_f32_16x16x32_bf16(hF[kf], ldw(fw1t+(size_t)(nf*16+row16)*HD+kf*32+ko), c,0,0,0);
            #pragma unroll
            for (int q=0;q<4;q++) tp[swz(kgrp*4+q,nf*16+row16)]=c[q];
        }
        #pragma unroll
        for (int kf=0;kf<3;kf++){
            float h[8]; ldtr8(tp,row16,kf*32+ko,h);
            #pragma unroll
            for (int j=0;j<8;j++) h[j]+=fb1[kf*32+ko+j];
            aBb[kf]=pack8f(h);
        }
        #pragma unroll 2
        for (int nf=6;nf<12;nf++){
            f32x4 c={0.f,0.f,0.f,0.f};
            #pragma unroll
            for (int kf=0;kf<3;kf++)
                c=__builtin_amdgcn_mfma_f32_16x16x32_bf16(hF[kf], ldw(fw1t+(size_t)(nf*16+row16)*HD+kf*32+ko), c,0,0,0);
            int col=(nf-6)*16+row16;
            #pragma unroll
            for (int q=0;q<4;q++) bmL[(wave*16+kgrp*4+q)*104 + col]=(__bf16)c[q];
        }
    }
    __syncthreads();   /* Bm + w2L + nbrB visible */

    /* ================= iteration loop ================= */
    #pragma unroll 1
    for (int it=0; it<NITER; ++it){
        /* ---------- EDGE (with next-d gather prefetch) ---------- */
        bf16x8 mF[3];
        {
            float b2c[6], b3c[6];
            #pragma unroll
            for (int nf=0;nf<6;nf++){ b2c[nf]=fb2[nf*16+row16]; b3c[nf]=20.0f*fb3[nf*16+row16]; }
            f32x4 acc[6];
            #pragma unroll
            for (int nf=0;nf<6;nf++) acc[nf]=(f32x4){0.f,0.f,0.f,0.f};
            const unsigned char* nbp = (const unsigned char*)nbrB;
            /* prime gather pipeline */
            bf16x8 v0,v1,v2;
            {
                const __bf16* vb = bmL + (int)nbp[gcell*DEG]*104 + ko;
                v0=ldw(vb); v1=ldw(vb+32); v2=ldw(vb+64);
            }
            #pragma unroll 2
            for (int d=0; d<DEG; d++){
                /* issue next-d gather before current compute */
                bf16x8 n0,n1,n2;
                {
                    int dn = (d+1<DEG)? d+1 : 0;
                    const __bf16* vb = bmL + (int)nbp[gcell*DEG+dn]*104 + ko;
                    n0=ldw(vb); n1=ldw(vb+32); n2=ldw(vb+64);
                }
                bf16x8 xf[3];
                {
                    float t[8];
                    #pragma unroll
                    for (int jj=0;jj<8;jj++) t[jj]=fmaxf((float)aBb[0][jj]+(float)v0[jj],0.f);
                    xf[0]=pack8f(t);
                    #pragma unroll
                    for (int jj=0;jj<8;jj++) t[jj]=fmaxf((float)aBb[1][jj]+(float)v1[jj],0.f);
                    xf[1]=pack8f(t);
                    #pragma unroll
                    for (int jj=0;jj<8;jj++) t[jj]=fmaxf((float)aBb[2][jj]+(float)v2[jj],0.f);
                    xf[2]=pack8f(t);
                }
                #pragma unroll
                for (int g2=0; g2<2; g2++){
                    f32x4 c[3];
                    #pragma unroll
                    for (int nf=0;nf<3;nf++) c[nf]=(f32x4){0.f,0.f,0.f,0.f};
                    #pragma unroll
                    for (int kf=0;kf<3;kf++)
                        #pragma unroll
                        for (int nf=0;nf<3;nf++)
                            c[nf]=__builtin_amdgcn_mfma_f32_16x16x32_bf16(xf[kf],
                                ldw(w2L+(size_t)((g2*3+nf)*16+row16)*104+kf*32+ko), c[nf],0,0,0);
                    #pragma unroll
                    for (int nf=0;nf<3;nf++)
                        #pragma unroll
                        for (int q=0;q<4;q++)
                            acc[g2*3+nf][q]+=fmaxf(c[nf][q]+b2c[g2*3+nf],0.f);
                }
                v0=n0; v1=n1; v2=n2;
            }
            /* layer 3 with hi/lo split */
            #pragma unroll
            for (int nf=0;nf<6;nf++)
                #pragma unroll
                for (int q=0;q<4;q++) tp[swz(kgrp*4+q,nf*16+row16)]=acc[nf][q];
            f32x4 c2[6];
            #pragma unroll
            for (int nf=0;nf<6;nf++) c2[nf]=(f32x4){0.f,0.f,0.f,0.f};
            #pragma unroll
            for (int kf=0;kf<3;kf++){
                float h[8]; ldtr8(tp,row16,kf*32+ko,h);
                bf16x8 hif, lof;
                #pragma unroll
                for (int j=0;j<8;j++){
                    unsigned short hs=f2bf(h[j]);
                    union{unsigned short s; __bf16 b;} u; u.s=hs;
                    hif[j]=u.b; lof[j]=(__bf16)(h[j]-bf2f(hs));
                }
                #pragma unroll 2
                for (int nf=0;nf<6;nf++){
                    bf16x8 w3f = ldw(fw3t + (size_t)(nf*16+row16)*HD + kf*32+ko);
                    c2[nf]=__builtin_amdgcn_mfma_f32_16x16x32_bf16(hif,w3f,c2[nf],0,0,0);
                    c2[nf]=__builtin_amdgcn_mfma_f32_16x16x32_bf16(lof,w3f,c2[nf],0,0,0);
                }
            }
            #pragma unroll
            for (int nf=0;nf<6;nf++)
                #pragma unroll
                for (int q=0;q<4;q++) tp[swz(kgrp*4+q,nf*16+row16)]=c2[nf][q]+b3c[nf];
            #pragma unroll
            for (int kf=0;kf<3;kf++) mF[kf]=packtr8(tp,row16,kf*32+ko);
        }
        __syncthreads();   /* all waves done reading bmL */

        /* ---------- g-MLP ---------- */
        bf16x8 xinF[3];
        {
            #pragma unroll 2
            for (int nf=0;nf<6;nf++){
                f32x4 c={0.f,0.f,0.f,0.f};
                #pragma unroll
                for (int kf=0;kf<3;kf++){
                    c=__builtin_amdgcn_mfma_f32_16x16x32_bf16(xF[kf], ldw(gw1t+(size_t)(nf*16+row16)*192+kf*32+ko), c,0,0,0);
                    c=__builtin_amdgcn_mfma_f32_16x16x32_bf16(mF[kf], ldw(gw1t+(size_t)(nf*16+row16)*192+96+kf*32+ko), c,0,0,0);
                }
                float b=gb1[nf*16+row16];
                #pragma unroll
                for (int q=0;q<4;q++) tp[swz(kgrp*4+q,nf*16+row16)]=fmaxf(c[q]+b,0.f);
            }
            bf16x8 ta[3];
            #pragma unroll
            for (int kf=0;kf<3;kf++) ta[kf]=packtr8(tp,row16,kf*32+ko);
            #pragma unroll 2
            for (int nf=0;nf<6;nf++){
                f32x4 c={0.f,0.f,0.f,0.f};
                #pragma unroll
                for (int kf=0;kf<3;kf++)
                    c=__builtin_amdgcn_mfma_f32_16x16x32_bf16(ta[kf], ldw(gw2t+(size_t)(nf*16+row16)*HD+kf*32+ko), c,0,0,0);
                float b=gb2[nf*16+row16];
                #pragma unroll
                for (int q=0;q<4;q++) tp[swz(kgrp*4+q,nf*16+row16)]=fmaxf(c[q]+b,0.f);
            }
            #pragma unroll
            for (int kf=0;kf<3;kf++) ta[kf]=packtr8(tp,row16,kf*32+ko);
            #pragma unroll 2
            for (int nf=0;nf<6;nf++){
                f32x4 c={0.f,0.f,0.f,0.f};
                #pragma unroll
                for (int kf=0;kf<3;kf++)
                    c=__builtin_amdgcn_mfma_f32_16x16x32_bf16(ta[kf], ldw(gw3t+(size_t)(nf*16+row16)*HD+kf*32+ko), c,0,0,0);
                float b=gb3[nf*16+row16];
                #pragma unroll
                for (int q=0;q<4;q++) tp[swz(kgrp*4+q,nf*16+row16)]=c[q]+b;
            }
            #pragma unroll
            for (int kf=0;kf<3;kf++) xinF[kf]=packtr8(tp,row16,kf*32+ko);
        }

        /* ---------- LSTM gates: per-nf, all 4 gates inside (C in LDS) ---------- */
        {
            #pragma unroll 1
            for (int nf=0;nf<6;nf++){
                const int col = nf*16+row16;
                f32x4 ci={0.f,0.f,0.f,0.f}, cf2={0.f,0.f,0.f,0.f},
                      cg={0.f,0.f,0.f,0.f}, co={0.f,0.f,0.f,0.f};
                #pragma unroll
                for (int kf=0;kf<3;kf++){
                    const int kk = kf*32+ko;
                    ci =__builtin_amdgcn_mfma_f32_16x16x32_bf16(xinF[kf], ldw(wiht+(size_t)(  0+col)*HD+kk), ci ,0,0,0);
                    ci =__builtin_amdgcn_mfma_f32_16x16x32_bf16(hF[kf],   ldw(whht+(size_t)(  0+col)*HD+kk), ci ,0,0,0);
                    cf2=__builtin_amdgcn_mfma_f32_16x16x32_bf16(xinF[kf], ldw(wiht+(size_t)( 96+col)*HD+kk), cf2,0,0,0);
                    cf2=__builtin_amdgcn_mfma_f32_16x16x32_bf16(hF[kf],   ldw(whht+(size_t)( 96+col)*HD+kk), cf2,0,0,0);
                    cg =__builtin_amdgcn_mfma_f32_16x16x32_bf16(xinF[kf], ldw(wiht+(size_t)(192+col)*HD+kk), cg ,0,0,0);
                    cg =__builtin_amdgcn_mfma_f32_16x16x32_bf16(hF[kf],   ldw(whht+(size_t)(192+col)*HD+kk), cg ,0,0,0);
                    co =__builtin_amdgcn_mfma_f32_16x16x32_bf16(xinF[kf], ldw(wiht+(size_t)(288+col)*HD+kk), co ,0,0,0);
                    co =__builtin_amdgcn_mfma_f32_16x16x32_bf16(hF[kf],   ldw(whht+(size_t)(288+col)*HD+kk), co ,0,0,0);
                }
                float bi=bih[    col]+bhh[    col];
                float bf=bih[ 96+col]+bhh[ 96+col];
                float bg=bih[192+col]+bhh[192+col];
                float bo=bih[288+col]+bhh[288+col];
                #pragma unroll
                for (int q=0;q<4;q++){
                    int cidx = (wave*16+kgrp*4+q)*100 + col;
                    float cnew = sigf(cf2[q]+bf)*cL[cidx] + sigf(ci[q]+bi)*tanh_fast(cg[q]+bg);
                    cL[cidx]=cnew;
                    float h2v = sigf(co[q]+bo)*tanh_fast(cnew);
                    tp[swz(kgrp*4+q, col)]=h2v;
                }
            }
            #pragma unroll
            for (int kf=0;kf<3;kf++) hF[kf]=packtr8(tp,row16,kf*32+ko);
        }

        /* ---------- next-iter A|Bm ---------- */
        if (it < NITER-1){
            #pragma unroll 2
            for (int nf=0;nf<6;nf++){
                f32x4 c={0.f,0.f,0.f,0.f};
                #pragma unroll
                for (int kf=0;kf<3;kf++)
                    c=__builtin_amdgcn_mfma_f32_16x16x32_bf16(hF[kf], ldw(fw1t+(size_t)(nf*16+row16)*HD+kf*32+ko), c,0,0,0);
                #pragma unroll
                for (int q=0;q<4;q++) tp[swz(kgrp*4+q,nf*16+row16)]=c[q];
            }
            #pragma unroll
            for (int kf=0;kf<3;kf++){
                float h[8]; ldtr8(tp,row16,kf*32+ko,h);
                #pragma unroll
                for (int j=0;j<8;j++) h[j]+=fb1[kf*32+ko+j];
                aBb[kf]=pack8f(h);
            }
            #pragma unroll 2
            for (int nf=6;nf<12;nf++){
                f32x4 c={0.f,0.f,0.f,0.f};
                #pragma unroll
                for (int kf=0;kf<3;kf++)
                    c=__builtin_amdgcn_mfma_f32_16x16x32_bf16(hF[kf], ldw(fw1t+(size_t)(nf*16+row16)*HD+kf*32+ko), c,0,0,0);
                int col=(nf-6)*16+row16;
                #pragma unroll
                for (int q=0;q<4;q++) bmL[(wave*16+kgrp*4+q)*104 + col]=(__bf16)c[q];
            }
        }

        /* ---------- readout MLP -> out ---------- */
        {
            #pragma unroll 2
            for (int nf=0;nf<6;nf++){
                f32x4 c={0.f,0.f,0.f,0.f};
                #pragma unroll
                for (int kf=0;kf<3;kf++)
                    c=__builtin_amdgcn_mfma_f32_16x16x32_bf16(hF[kf], ldw(rw1t+(size_t)(nf*16+row16)*HD+kf*32+ko), c,0,0,0);
                float b=rb1[nf*16+row16];
                #pragma unroll
                for (int q=0;q<4;q++) tp[swz(kgrp*4+q,nf*16+row16)]=fmaxf(c[q]+b,0.f);
            }
            bf16x8 ta[3];
            #pragma unroll
            for (int kf=0;kf<3;kf++) ta[kf]=packtr8(tp,row16,kf*32+ko);
            #pragma unroll 2
            for (int nf=0;nf<6;nf++){
                f32x4 c={0.f,0.f,0.f,0.f};
                #pragma unroll
                for (int kf=0;kf<3;kf++)
                    c=__builtin_amdgcn_mfma_f32_16x16x32_bf16(ta[kf], ldw(rw2t+(size_t)(nf*16+row16)*HD+kf*32+ko), c,0,0,0);
                float b=rb2[nf*16+row16];
                #pragma unroll
                for (int q=0;q<4;q++) tp[swz(kgrp*4+q,nf*16+row16)]=fmaxf(c[q]+b,0.f);
            }
            #pragma unroll
            for (int kf=0;kf<3;kf++) ta[kf]=packtr8(tp,row16,kf*32+ko);
            f32x4 c={0.f,0.f,0.f,0.f};
            #pragma unroll
            for (int kf=0;kf<3;kf++)
                c=__builtin_amdgcn_mfma_f32_16x16x32_bf16(ta[kf], ldw(rw3t+(size_t)row16*HD+kf*32+ko), c,0,0,0);
            float b=rb3[row16];
            #pragma unroll
            for (int q=0;q<4;q++){
                int cell = wave*16 + kgrp*4 + q;
                if (cell < Nc)
                    out[((size_t)it*Rtot + (size_t)p*Nc + cell)*Edim + row16] = c[q]+b;
            }
        }
        __syncthreads();   /* new Bm written before next iter's edge reads */
    }
}

extern "C" void kernel_launch(void* const* d_in, const int* in_sizes, int n_in,
                              void* d_out, int out_size, void* d_ws, size_t ws_size,
                              hipStream_t stream) {
    const int*   grids  = (const int*)  d_in[0];
    const int*   nbr    = (const int*)  d_in[1];
    const float* c0     = (const float*)d_in[3];
    const float* embw   = (const float*)d_in[4];
    const float* in_w1  = (const float*)d_in[5];
    const float* in_b1  = (const float*)d_in[6];
    const float* in_w2  = (const float*)d_in[7];
    const float* in_b2  = (const float*)d_in[8];
    const float* in_w3  = (const float*)d_in[9];
    const float* in_b3  = (const float*)d_in[10];
    const float* f_w1   = (const float*)d_in[11];
    const float* f_b1   = (const float*)d_in[12];
    const float* f_w2   = (const float*)d_in[13];
    const float* f_b2   = (const float*)d_in[14];
    const float* f_w3   = (const float*)d_in[15];
    const float* f_b3   = (const float*)d_in[16];
    const float* g_w1   = (const float*)d_in[17];
    const float* g_b1   = (const float*)d_in[18];
    const float* g_w2   = (const float*)d_in[19];
    const float* g_b2   = (const float*)d_in[20];
    const float* g_w3   = (const float*)d_in[21];
    const float* g_b3   = (const float*)d_in[22];
    const float* wih    = (const float*)d_in[23];
    const float* whh    = (const float*)d_in[24];
    const float* bih    = (const float*)d_in[25];
    const float* bhh    = (const float*)d_in[26];
    const float* r_w1   = (const float*)d_in[27];
    const float* r_b1   = (const float*)d_in[28];
    const float* r_w2   = (const float*)d_in[29];
    const float* r_b2   = (const float*)d_in[30];
    const float* r_w3   = (const float*)d_in[31];
    const float* r_b3   = (const float*)d_in[32];

    __bf16* wt = (__bf16*)d_ws;
    __bf16* wp = wt + WT_TOTAL;
    float* out = (float*)d_out;

    hipLaunchKernelGGL(k_prep, dim3((WT_TOTAL+255)/256), dim3(256), 0, stream,
        f_w1, f_w2, f_w3, g_w1, g_w2, g_w3, wih, whh, r_w1, r_w2, r_w3,
        in_w1, in_w2, in_w3, wt);
    hipLaunchKernelGGL(k_prep2, dim3((96*104+255)/256), dim3(256), 0, stream,
        f_w2, wp);

    hipLaunchKernelGGL(k_all, dim3(Bsz), dim3(384), 0, stream,
        grids, nbr, c0, embw, wt, wp,
        in_b1, in_b2, in_b3,
        f_b1, f_b2, f_b3,
        g_b1, g_b2, g_b3,
        bih, bhh,
        r_b1, r_b2, r_b3,
        out);
}

// Round 14
// 442.241 us; speedup vs baseline: 1.9101x; 1.0013x over previous
//
#include <hip/hip_runtime.h>
#include <math.h>

#define Bsz 512
#define Nc  81
#define Rtot (Bsz*Nc)     /* 41472 rows */
#define DEG 20
#define Edim 16
#define HD  96
#define NITER 4

typedef __attribute__((ext_vector_type(8))) __bf16 bf16x8;
typedef __attribute__((ext_vector_type(4))) float f32x4;

__device__ __forceinline__ float sigf(float x){ return 1.0f/(1.0f+__expf(-x)); }
__device__ __forceinline__ float tanh_fast(float x){ return 2.0f/(1.0f+__expf(-2.0f*x)) - 1.0f; }

__device__ __forceinline__ unsigned short f2bf(float f){
    union{float f; unsigned u;} v; v.f=f;
    unsigned r = v.u + 0x7fff + ((v.u>>16)&1);
    return (unsigned short)(r>>16);
}
__device__ __forceinline__ float bf2f(unsigned short s){
    union{unsigned u; float f;} v; v.u=((unsigned)s)<<16; return v.f;
}
__device__ __forceinline__ bf16x8 pack8f(const float* x){
    bf16x8 r;
    #pragma unroll
    for (int j=0;j<8;j++) r[j]=(__bf16)x[j];
    return r;
}
__device__ __forceinline__ bf16x8 ldw(const __bf16* p){ return *(const bf16x8*)p; }

/* ---- swizzled LDS tile [16][96] fp32 (XOR 16B-chunk idx with row&7) ---- */
__device__ __forceinline__ int swz(int row, int col){
    return row*96 + ((((col>>2) ^ (row&7))<<2) | (col&3));
}
__device__ __forceinline__ void ldtr8(const float* tp, int row, int c, float* o){
    const int r96 = row*96, rho = row&7;
    const float4 a = *(const float4*)(tp + r96 + ((((c>>2)  ) ^ rho)<<2));
    const float4 b = *(const float4*)(tp + r96 + ((((c>>2)+1) ^ rho)<<2));
    o[0]=a.x;o[1]=a.y;o[2]=a.z;o[3]=a.w;o[4]=b.x;o[5]=b.y;o[6]=b.z;o[7]=b.w;
}
__device__ __forceinline__ bf16x8 packtr8(const float* tp, int row, int c){
    float t[8]; ldtr8(tp,row,c,t); return pack8f(t);
}

/* bf16 transposed-weight offsets inside ws (elements) — [n][k] layouts */
#define OFF_FW1T 0          /* [192][96] */
#define OFF_FW2T 18432
#define OFF_FW3T 27648
#define OFF_GW1T 36864      /* [96][192] */
#define OFF_GW2T 55296
#define OFF_GW3T 64512
#define OFF_WIHT 73728      /* [384][96] */
#define OFF_WHHT 110592
#define OFF_RW1T 147456
#define OFF_RW2T 156672
#define OFF_RW3T 165888     /* [16][96] */
#define OFF_IW1T 167424     /* [96][32] */
#define OFF_IW2T 170496
#define OFF_IW3T 179712
#define WT_TOTAL 188928

/* ---------------- k_prep: bf16 transposed weights ---------------- */
__global__ __launch_bounds__(256) void k_prep(
    const float* __restrict__ fw1, const float* __restrict__ fw2, const float* __restrict__ fw3,
    const float* __restrict__ gw1, const float* __restrict__ gw2, const float* __restrict__ gw3,
    const float* __restrict__ wih, const float* __restrict__ whh,
    const float* __restrict__ rw1, const float* __restrict__ rw2, const float* __restrict__ rw3,
    const float* __restrict__ iw1, const float* __restrict__ iw2, const float* __restrict__ iw3,
    __bf16* __restrict__ wt)
{
    int i = blockIdx.x*256 + threadIdx.x;
    if (i >= WT_TOTAL) return;
    int j = i;
    if (j < 18432){ int n=j/96, k=j-n*96;
        wt[OFF_FW1T+j] = (__bf16)(n<96 ? fw1[k*96+n] : fw1[(96+k)*96+(n-96)]); return; }
    j -= 18432;
    if (j < 9216){ int n=j/96, k=j-n*96; wt[OFF_FW2T+j]=(__bf16)fw2[k*96+n]; return; }
    j -= 9216;
    if (j < 9216){ int n=j/96, k=j-n*96; wt[OFF_FW3T+j]=(__bf16)fw3[k*96+n]; return; }
    j -= 9216;
    if (j < 18432){ int n=j/192, k=j-n*192; wt[OFF_GW1T+j]=(__bf16)gw1[k*96+n]; return; }
    j -= 18432;
    if (j < 9216){ int n=j/96, k=j-n*96; wt[OFF_GW2T+j]=(__bf16)gw2[k*96+n]; return; }
    j -= 9216;
    if (j < 9216){ int n=j/96, k=j-n*96; wt[OFF_GW3T+j]=(__bf16)gw3[k*96+n]; return; }
    j -= 9216;
    if (j < 36864){ int n=j/96, k=j-n*96; wt[OFF_WIHT+j]=(__bf16)wih[k*384+n]; return; }
    j -= 36864;
    if (j < 36864){ int n=j/96, k=j-n*96; wt[OFF_WHHT+j]=(__bf16)whh[k*384+n]; return; }
    j -= 36864;
    if (j < 9216){ int n=j/96, k=j-n*96; wt[OFF_RW1T+j]=(__bf16)rw1[k*96+n]; return; }
    j -= 9216;
    if (j < 9216){ int n=j/96, k=j-n*96; wt[OFF_RW2T+j]=(__bf16)rw2[k*96+n]; return; }
    j -= 9216;
    if (j < 1536){ int n=j/96, k=j-n*96; wt[OFF_RW3T+j]=(__bf16)rw3[k*16+n]; return; }
    j -= 1536;
    if (j < 3072){ int n=j>>5, k=j&31; wt[OFF_IW1T+j]=(__bf16)iw1[(k&15)*96+n]; return; }
    j -= 3072;
    if (j < 9216){ int n=j/96, k=j-n*96; wt[OFF_IW2T+j]=(__bf16)iw2[k*96+n]; return; }
    j -= 9216;
    { int n=j/96, k=j-n*96; wt[OFF_IW3T+j]=(__bf16)iw3[k*96+n]; }
}

/* ---------------- k_prep2: fw2 padded [96][104] for LDS staging ---------------- */
__global__ __launch_bounds__(256) void k_prep2(
    const float* __restrict__ fw2, __bf16* __restrict__ wp)
{
    int i = blockIdx.x*256 + threadIdx.x;
    if (i >= 96*104) return;
    int n=i/104, k=i-n*104;
    wp[i] = (__bf16)((k<96)? fw2[k*96+n] : 0.f);
}

/* ---------------- k_all: full 4-iteration RRN, one block per puzzle ----------------
   R13 champion + widened MLP window (unroll 3) on the five register-slack
   weight-streaming loops (g-L2/L3, A/Bm, readout L1/L2). Edge, g-L1, LSTM
   unchanged (those phases are at the register peak). */
__global__ __launch_bounds__(384,2) void k_all(
    const int* __restrict__ grids, const int* __restrict__ nbr,
    const float* __restrict__ c0, const float* __restrict__ embw,
    const __bf16* __restrict__ wt, const __bf16* __restrict__ wp,
    const float* __restrict__ ib1, const float* __restrict__ ib2, const float* __restrict__ ib3,
    const float* __restrict__ fb1, const float* __restrict__ fb2, const float* __restrict__ fb3,
    const float* __restrict__ gb1, const float* __restrict__ gb2, const float* __restrict__ gb3,
    const float* __restrict__ bih, const float* __restrict__ bhh,
    const float* __restrict__ rb1, const float* __restrict__ rb2, const float* __restrict__ rb3,
    float* __restrict__ out)
{
    __shared__ __bf16 bmL[96*104];      /* Bm, padded rows (19968 B) */
    __shared__ __bf16 w2L[96*104];      /* fw2 padded (19968 B) */
    __shared__ float  scr[6*16*96];     /* per-wave transpose scratch (36864 B) */
    __shared__ float  cL[96*100];       /* LSTM cell state (38400 B) */
    __shared__ unsigned nbrB[405];      /* packed neighbor bytes (1620 B) */

    const int tid = threadIdx.x;
    const int wave = tid/64, lane = tid&63;
    const int row16 = lane&15, kgrp = lane>>4, ko = kgrp*8;
    const int p = blockIdx.x;
    const int cellR = wave*16 + row16;
    const int gcell = (cellR < Nc) ? cellR : Nc-1;
    float* tp = scr + wave*(16*96);

    const __bf16 *iw1t=wt+OFF_IW1T, *iw2t=wt+OFF_IW2T, *iw3t=wt+OFF_IW3T;
    const __bf16 *fw1t=wt+OFF_FW1T, *fw3t=wt+OFF_FW3T;
    const __bf16 *gw1t=wt+OFF_GW1T, *gw2t=wt+OFF_GW2T, *gw3t=wt+OFF_GW3T;
    const __bf16 *wiht=wt+OFF_WIHT, *whht=wt+OFF_WHHT;
    const __bf16 *rw1t=wt+OFF_RW1T, *rw2t=wt+OFF_RW2T, *rw3t=wt+OFF_RW3T;

    /* ---- stage fw2 + nbr bytes ---- */
    {
        const int4* s=(const int4*)wp; int4* d=(int4*)w2L;
        for (int i=tid;i<(96*104/8);i+=384) d[i]=s[i];
    }
    for (int i=tid;i<405;i+=384){
        unsigned b0=(unsigned)nbr[4*i], b1=(unsigned)nbr[4*i+1],
                 b2=(unsigned)nbr[4*i+2], b3=(unsigned)nbr[4*i+3];
        nbrB[i] = b0 | (b1<<8) | (b2<<16) | (b3<<24);
    }

    /* ---- persistent state (registers) ---- */
    bf16x8 xF[3], hF[3];
    bf16x8 aBb[3];

    /* ---- C init -> LDS ---- */
    #pragma unroll
    for (int nf=0;nf<6;nf++)
        #pragma unroll
        for (int q=0;q<4;q++){
            int cell = wave*16 + kgrp*4 + q;
            cL[cell*100 + nf*16+row16] = (cell<Nc) ? c0[((size_t)p*Nc+cell)*HD + nf*16+row16] : 0.f;
        }

    /* ================= embed + input MLP (hi/lo K=32 layer 1) ================= */
    {
        const int g = grids[p*Nc + gcell];
        const float* ew = embw + g*Edim + (kgrp&1)*8;
        bf16x8 ef;
        #pragma unroll
        for (int j=0;j<8;j++){
            float e = ew[j];
            ef[j] = (kgrp<2) ? (__bf16)e : (__bf16)(e - bf2f(f2bf(e)));
        }
        #pragma unroll 2
        for (int nf=0;nf<6;nf++){
            f32x4 c={0.f,0.f,0.f,0.f};
            c=__builtin_amdgcn_mfma_f32_16x16x32_bf16(ef, ldw(iw1t+(size_t)(nf*16+row16)*32+ko), c,0,0,0);
            float b=ib1[nf*16+row16];
            #pragma unroll
            for (int q=0;q<4;q++) tp[swz(kgrp*4+q,nf*16+row16)]=fmaxf(c[q]+b,0.f);
        }
        bf16x8 ta[3];
        #pragma unroll
        for (int kf=0;kf<3;kf++) ta[kf]=packtr8(tp,row16,kf*32+ko);
        #pragma unroll 2
        for (int nf=0;nf<6;nf++){
            f32x4 c={0.f,0.f,0.f,0.f};
            #pragma unroll
            for (int kf=0;kf<3;kf++)
                c=__builtin_amdgcn_mfma_f32_16x16x32_bf16(ta[kf], ldw(iw2t+(size_t)(nf*16+row16)*HD+kf*32+ko), c,0,0,0);
            float b=ib2[nf*16+row16];
            #pragma unroll
            for (int q=0;q<4;q++) tp[swz(kgrp*4+q,nf*16+row16)]=fmaxf(c[q]+b,0.f);
        }
        #pragma unroll
        for (int kf=0;kf<3;kf++) ta[kf]=packtr8(tp,row16,kf*32+ko);
        #pragma unroll 2
        for (int nf=0;nf<6;nf++){
            f32x4 c={0.f,0.f,0.f,0.f};
            #pragma unroll
            for (int kf=0;kf<3;kf++)
                c=__builtin_amdgcn_mfma_f32_16x16x32_bf16(ta[kf], ldw(iw3t+(size_t)(nf*16+row16)*HD+kf*32+ko), c,0,0,0);
            float b=ib3[nf*16+row16];
            #pragma unroll
            for (int q=0;q<4;q++) tp[swz(kgrp*4+q,nf*16+row16)]=c[q]+b;
        }
        #pragma unroll
        for (int kf=0;kf<3;kf++){ xF[kf]=packtr8(tp,row16,kf*32+ko); hF[kf]=xF[kf]; }
    }
    /* ---- initial A|Bm = h0 @ fw1 ---- */
    {
        #pragma unroll 3
        for (int nf=0;nf<6;nf++){
            f32x4 c={0.f,0.f,0.f,0.f};
            #pragma unroll
            for (int kf=0;kf<3;kf++)
                c=__builtin_amdgcn_mfma_f32_16x16x32_bf16(hF[kf], ldw(fw1t+(size_t)(nf*16+row16)*HD+kf*32+ko), c,0,0,0);
            #pragma unroll
            for (int q=0;q<4;q++) tp[swz(kgrp*4+q,nf*16+row16)]=c[q];
        }
        #pragma unroll
        for (int kf=0;kf<3;kf++){
            float h[8]; ldtr8(tp,row16,kf*32+ko,h);
            #pragma unroll
            for (int j=0;j<8;j++) h[j]+=fb1[kf*32+ko+j];
            aBb[kf]=pack8f(h);
        }
        #pragma unroll 3
        for (int nf=6;nf<12;nf++){
            f32x4 c={0.f,0.f,0.f,0.f};
            #pragma unroll
            for (int kf=0;kf<3;kf++)
                c=__builtin_amdgcn_mfma_f32_16x16x32_bf16(hF[kf], ldw(fw1t+(size_t)(nf*16+row16)*HD+kf*32+ko), c,0,0,0);
            int col=(nf-6)*16+row16;
            #pragma unroll
            for (int q=0;q<4;q++) bmL[(wave*16+kgrp*4+q)*104 + col]=(__bf16)c[q];
        }
    }
    __syncthreads();

    /* ================= iteration loop ================= */
    #pragma unroll 1
    for (int it=0; it<NITER; ++it){
        /* ---------- EDGE (with next-d gather prefetch) ---------- */
        bf16x8 mF[3];
        {
            float b2c[6], b3c[6];
            #pragma unroll
            for (int nf=0;nf<6;nf++){ b2c[nf]=fb2[nf*16+row16]; b3c[nf]=20.0f*fb3[nf*16+row16]; }
            f32x4 acc[6];
            #pragma unroll
            for (int nf=0;nf<6;nf++) acc[nf]=(f32x4){0.f,0.f,0.f,0.f};
            const unsigned char* nbp = (const unsigned char*)nbrB;
            bf16x8 v0,v1,v2;
            {
                const __bf16* vb = bmL + (int)nbp[gcell*DEG]*104 + ko;
                v0=ldw(vb); v1=ldw(vb+32); v2=ldw(vb+64);
            }
            #pragma unroll 2
            for (int d=0; d<DEG; d++){
                bf16x8 n0,n1,n2;
                {
                    int dn = (d+1<DEG)? d+1 : 0;
                    const __bf16* vb = bmL + (int)nbp[gcell*DEG+dn]*104 + ko;
                    n0=ldw(vb); n1=ldw(vb+32); n2=ldw(vb+64);
                }
                bf16x8 xf[3];
                {
                    float t[8];
                    #pragma unroll
                    for (int jj=0;jj<8;jj++) t[jj]=fmaxf((float)aBb[0][jj]+(float)v0[jj],0.f);
                    xf[0]=pack8f(t);
                    #pragma unroll
                    for (int jj=0;jj<8;jj++) t[jj]=fmaxf((float)aBb[1][jj]+(float)v1[jj],0.f);
                    xf[1]=pack8f(t);
                    #pragma unroll
                    for (int jj=0;jj<8;jj++) t[jj]=fmaxf((float)aBb[2][jj]+(float)v2[jj],0.f);
                    xf[2]=pack8f(t);
                }
                #pragma unroll
                for (int g2=0; g2<2; g2++){
                    f32x4 c[3];
                    #pragma unroll
                    for (int nf=0;nf<3;nf++) c[nf]=(f32x4){0.f,0.f,0.f,0.f};
                    #pragma unroll
                    for (int kf=0;kf<3;kf++)
                        #pragma unroll
                        for (int nf=0;nf<3;nf++)
                            c[nf]=__builtin_amdgcn_mfma_f32_16x16x32_bf16(xf[kf],
                                ldw(w2L+(size_t)((g2*3+nf)*16+row16)*104+kf*32+ko), c[nf],0,0,0);
                    #pragma unroll
                    for (int nf=0;nf<3;nf++)
                        #pragma unroll
                        for (int q=0;q<4;q++)
                            acc[g2*3+nf][q]+=fmaxf(c[nf][q]+b2c[g2*3+nf],0.f);
                }
                v0=n0; v1=n1; v2=n2;
            }
            /* layer 3 with hi/lo split */
            #pragma unroll
            for (int nf=0;nf<6;nf++)
                #pragma unroll
                for (int q=0;q<4;q++) tp[swz(kgrp*4+q,nf*16+row16)]=acc[nf][q];
            f32x4 c2[6];
            #pragma unroll
            for (int nf=0;nf<6;nf++) c2[nf]=(f32x4){0.f,0.f,0.f,0.f};
            #pragma unroll
            for (int kf=0;kf<3;kf++){
                float h[8]; ldtr8(tp,row16,kf*32+ko,h);
                bf16x8 hif, lof;
                #pragma unroll
                for (int j=0;j<8;j++){
                    unsigned short hs=f2bf(h[j]);
                    union{unsigned short s; __bf16 b;} u; u.s=hs;
                    hif[j]=u.b; lof[j]=(__bf16)(h[j]-bf2f(hs));
                }
                #pragma unroll 2
                for (int nf=0;nf<6;nf++){
                    bf16x8 w3f = ldw(fw3t + (size_t)(nf*16+row16)*HD + kf*32+ko);
                    c2[nf]=__builtin_amdgcn_mfma_f32_16x16x32_bf16(hif,w3f,c2[nf],0,0,0);
                    c2[nf]=__builtin_amdgcn_mfma_f32_16x16x32_bf16(lof,w3f,c2[nf],0,0,0);
                }
            }
            #pragma unroll
            for (int nf=0;nf<6;nf++)
                #pragma unroll
                for (int q=0;q<4;q++) tp[swz(kgrp*4+q,nf*16+row16)]=c2[nf][q]+b3c[nf];
            #pragma unroll
            for (int kf=0;kf<3;kf++) mF[kf]=packtr8(tp,row16,kf*32+ko);
        }
        __syncthreads();

        /* ---------- g-MLP ---------- */
        bf16x8 xinF[3];
        {
            #pragma unroll 2
            for (int nf=0;nf<6;nf++){
                f32x4 c={0.f,0.f,0.f,0.f};
                #pragma unroll
                for (int kf=0;kf<3;kf++){
                    c=__builtin_amdgcn_mfma_f32_16x16x32_bf16(xF[kf], ldw(gw1t+(size_t)(nf*16+row16)*192+kf*32+ko), c,0,0,0);
                    c=__builtin_amdgcn_mfma_f32_16x16x32_bf16(mF[kf], ldw(gw1t+(size_t)(nf*16+row16)*192+96+kf*32+ko), c,0,0,0);
                }
                float b=gb1[nf*16+row16];
                #pragma unroll
                for (int q=0;q<4;q++) tp[swz(kgrp*4+q,nf*16+row16)]=fmaxf(c[q]+b,0.f);
            }
            bf16x8 ta[3];
            #pragma unroll
            for (int kf=0;kf<3;kf++) ta[kf]=packtr8(tp,row16,kf*32+ko);
            #pragma unroll 3
            for (int nf=0;nf<6;nf++){
                f32x4 c={0.f,0.f,0.f,0.f};
                #pragma unroll
                for (int kf=0;kf<3;kf++)
                    c=__builtin_amdgcn_mfma_f32_16x16x32_bf16(ta[kf], ldw(gw2t+(size_t)(nf*16+row16)*HD+kf*32+ko), c,0,0,0);
                float b=gb2[nf*16+row16];
                #pragma unroll
                for (int q=0;q<4;q++) tp[swz(kgrp*4+q,nf*16+row16)]=fmaxf(c[q]+b,0.f);
            }
            #pragma unroll
            for (int kf=0;kf<3;kf++) ta[kf]=packtr8(tp,row16,kf*32+ko);
            #pragma unroll 3
            for (int nf=0;nf<6;nf++){
                f32x4 c={0.f,0.f,0.f,0.f};
                #pragma unroll
                for (int kf=0;kf<3;kf++)
                    c=__builtin_amdgcn_mfma_f32_16x16x32_bf16(ta[kf], ldw(gw3t+(size_t)(nf*16+row16)*HD+kf*32+ko), c,0,0,0);
                float b=gb3[nf*16+row16];
                #pragma unroll
                for (int q=0;q<4;q++) tp[swz(kgrp*4+q,nf*16+row16)]=c[q]+b;
            }
            #pragma unroll
            for (int kf=0;kf<3;kf++) xinF[kf]=packtr8(tp,row16,kf*32+ko);
        }

        /* ---------- LSTM gates: per-nf, all 4 gates inside (C in LDS) ---------- */
        {
            #pragma unroll 1
            for (int nf=0;nf<6;nf++){
                const int col = nf*16+row16;
                f32x4 ci={0.f,0.f,0.f,0.f}, cf2={0.f,0.f,0.f,0.f},
                      cg={0.f,0.f,0.f,0.f}, co={0.f,0.f,0.f,0.f};
                #pragma unroll
                for (int kf=0;kf<3;kf++){
                    const int kk = kf*32+ko;
                    ci =__builtin_amdgcn_mfma_f32_16x16x32_bf16(xinF[kf], ldw(wiht+(size_t)(  0+col)*HD+kk), ci ,0,0,0);
                    ci =__builtin_amdgcn_mfma_f32_16x16x32_bf16(hF[kf],   ldw(whht+(size_t)(  0+col)*HD+kk), ci ,0,0,0);
                    cf2=__builtin_amdgcn_mfma_f32_16x16x32_bf16(xinF[kf], ldw(wiht+(size_t)( 96+col)*HD+kk), cf2,0,0,0);
                    cf2=__builtin_amdgcn_mfma_f32_16x16x32_bf16(hF[kf],   ldw(whht+(size_t)( 96+col)*HD+kk), cf2,0,0,0);
                    cg =__builtin_amdgcn_mfma_f32_16x16x32_bf16(xinF[kf], ldw(wiht+(size_t)(192+col)*HD+kk), cg ,0,0,0);
                    cg =__builtin_amdgcn_mfma_f32_16x16x32_bf16(hF[kf],   ldw(whht+(size_t)(192+col)*HD+kk), cg ,0,0,0);
                    co =__builtin_amdgcn_mfma_f32_16x16x32_bf16(xinF[kf], ldw(wiht+(size_t)(288+col)*HD+kk), co ,0,0,0);
                    co =__builtin_amdgcn_mfma_f32_16x16x32_bf16(hF[kf],   ldw(whht+(size_t)(288+col)*HD+kk), co ,0,0,0);
                }
                float bi=bih[    col]+bhh[    col];
                float bf=bih[ 96+col]+bhh[ 96+col];
                float bg=bih[192+col]+bhh[192+col];
                float bo=bih[288+col]+bhh[288+col];
                #pragma unroll
                for (int q=0;q<4;q++){
                    int cidx = (wave*16+kgrp*4+q)*100 + col;
                    float cnew = sigf(cf2[q]+bf)*cL[cidx] + sigf(ci[q]+bi)*tanh_fast(cg[q]+bg);
                    cL[cidx]=cnew;
                    float h2v = sigf(co[q]+bo)*tanh_fast(cnew);
                    tp[swz(kgrp*4+q, col)]=h2v;
                }
            }
            #pragma unroll
            for (int kf=0;kf<3;kf++) hF[kf]=packtr8(tp,row16,kf*32+ko);
        }

        /* ---------- next-iter A|Bm ---------- */
        if (it < NITER-1){
            #pragma unroll 3
            for (int nf=0;nf<6;nf++){
                f32x4 c={0.f,0.f,0.f,0.f};
                #pragma unroll
                for (int kf=0;kf<3;kf++)
                    c=__builtin_amdgcn_mfma_f32_16x16x32_bf16(hF[kf], ldw(fw1t+(size_t)(nf*16+row16)*HD+kf*32+ko), c,0,0,0);
                #pragma unroll
                for (int q=0;q<4;q++) tp[swz(kgrp*4+q,nf*16+row16)]=c[q];
            }
            #pragma unroll
            for (int kf=0;kf<3;kf++){
                float h[8]; ldtr8(tp,row16,kf*32+ko,h);
                #pragma unroll
                for (int j=0;j<8;j++) h[j]+=fb1[kf*32+ko+j];
                aBb[kf]=pack8f(h);
            }
            #pragma unroll 3
            for (int nf=6;nf<12;nf++){
                f32x4 c={0.f,0.f,0.f,0.f};
                #pragma unroll
                for (int kf=0;kf<3;kf++)
                    c=__builtin_amdgcn_mfma_f32_16x16x32_bf16(hF[kf], ldw(fw1t+(size_t)(nf*16+row16)*HD+kf*32+ko), c,0,0,0);
                int col=(nf-6)*16+row16;
                #pragma unroll
                for (int q=0;q<4;q++) bmL[(wave*16+kgrp*4+q)*104 + col]=(__bf16)c[q];
            }
        }

        /* ---------- readout MLP -> out ---------- */
        {
            #pragma unroll 3
            for (int nf=0;nf<6;nf++){
                f32x4 c={0.f,0.f,0.f,0.f};
                #pragma unroll
                for (int kf=0;kf<3;kf++)
                    c=__builtin_amdgcn_mfma_f32_16x16x32_bf16(hF[kf], ldw(rw1t+(size_t)(nf*16+row16)*HD+kf*32+ko), c,0,0,0);
                float b=rb1[nf*16+row16];
                #pragma unroll
                for (int q=0;q<4;q++) tp[swz(kgrp*4+q,nf*16+row16)]=fmaxf(c[q]+b,0.f);
            }
            bf16x8 ta[3];
            #pragma unroll
            for (int kf=0;kf<3;kf++) ta[kf]=packtr8(tp,row16,kf*32+ko);
            #pragma unroll 3
            for (int nf=0;nf<6;nf++){
                f32x4 c={0.f,0.f,0.f,0.f};
                #pragma unroll
                for (int kf=0;kf<3;kf++)
                    c=__builtin_amdgcn_mfma_f32_16x16x32_bf16(ta[kf], ldw(rw2t+(size_t)(nf*16+row16)*HD+kf*32+ko), c,0,0,0);
                float b=rb2[nf*16+row16];
                #pragma unroll
                for (int q=0;q<4;q++) tp[swz(kgrp*4+q,nf*16+row16)]=fmaxf(c[q]+b,0.f);
            }
            #pragma unroll
            for (int kf=0;kf<3;kf++) ta[kf]=packtr8(tp,row16,kf*32+ko);
            f32x4 c={0.f,0.f,0.f,0.f};
            #pragma unroll
            for (int kf=0;kf<3;kf++)
                c=__builtin_amdgcn_mfma_f32_16x16x32_bf16(ta[kf], ldw(rw3t+(size_t)row16*HD+kf*32+ko), c,0,0,0);
            float b=rb3[row16];
            #pragma unroll
            for (int q=0;q<4;q++){
                int cell = wave*16 + kgrp*4 + q;
                if (cell < Nc)
                    out[((size_t)it*Rtot + (size_t)p*Nc + cell)*Edim + row16] = c[q]+b;
            }
        }
        __syncthreads();
    }
}

extern "C" void kernel_launch(void* const* d_in, const int* in_sizes, int n_in,
                              void* d_out, int out_size, void* d_ws, size_t ws_size,
                              hipStream_t stream) {
    const int*   grids  = (const int*)  d_in[0];
    const int*   nbr    = (const int*)  d_in[1];
    const float* c0     = (const float*)d_in[3];
    const float* embw   = (const float*)d_in[4];
    const float* in_w1  = (const float*)d_in[5];
    const float* in_b1  = (const float*)d_in[6];
    const float* in_w2  = (const float*)d_in[7];
    const float* in_b2  = (const float*)d_in[8];
    const float* in_w3  = (const float*)d_in[9];
    const float* in_b3  = (const float*)d_in[10];
    const float* f_w1   = (const float*)d_in[11];
    const float* f_b1   = (const float*)d_in[12];
    const float* f_w2   = (const float*)d_in[13];
    const float* f_b2   = (const float*)d_in[14];
    const float* f_w3   = (const float*)d_in[15];
    const float* f_b3   = (const float*)d_in[16];
    const float* g_w1   = (const float*)d_in[17];
    const float* g_b1   = (const float*)d_in[18];
    const float* g_w2   = (const float*)d_in[19];
    const float* g_b2   = (const float*)d_in[20];
    const float* g_w3   = (const float*)d_in[21];
    const float* g_b3   = (const float*)d_in[22];
    const float* wih    = (const float*)d_in[23];
    const float* whh    = (const float*)d_in[24];
    const float* bih    = (const float*)d_in[25];
    const float* bhh    = (const float*)d_in[26];
    const float* r_w1   = (const float*)d_in[27];
    const float* r_b1   = (const float*)d_in[28];
    const float* r_w2   = (const float*)d_in[29];
    const float* r_b2   = (const float*)d_in[30];
    const float* r_w3   = (const float*)d_in[31];
    const float* r_b3   = (const float*)d_in[32];

    __bf16* wt = (__bf16*)d_ws;
    __bf16* wp = wt + WT_TOTAL;
    float* out = (float*)d_out;

    hipLaunchKernelGGL(k_prep, dim3((WT_TOTAL+255)/256), dim3(256), 0, stream,
        f_w1, f_w2, f_w3, g_w1, g_w2, g_w3, wih, whh, r_w1, r_w2, r_w3,
        in_w1, in_w2, in_w3, wt);
    hipLaunchKernelGGL(k_prep2, dim3((96*104+255)/256), dim3(256), 0, stream,
        f_w2, wp);

    hipLaunchKernelGGL(k_all, dim3(Bsz), dim3(384), 0, stream,
        grids, nbr, c0, embw, wt, wp,
        in_b1, in_b2, in_b3,
        f_b1, f_b2, f_b3,
        g_b1, g_b2, g_b3,
        bih, bhh,
        r_b1, r_b2, r_b3,
        out);
}